// Round 1
// baseline (2954.038 us; speedup 1.0000x reference)
//
#include <hip/hip_runtime.h>
#include <cstdint>
#include <cstddef>

using bf16x8 = __attribute__((ext_vector_type(8))) short;
using f32x4  = __attribute__((ext_vector_type(4))) float;

#define HDIM 768
#define H4DIM 3072
#define NDIM 64
#define SEQ 2048
#define NBATCH 2
#define MROWS 4096
#define VOCAB 32000
#define KTAPS 128

__device__ __forceinline__ unsigned short f2bf(float f) {
    union { float f; unsigned u; } v; v.f = f;
    unsigned r = v.u + 0x7fffu + ((v.u >> 16) & 1u);
    return (unsigned short)(r >> 16);
}

// ---------------- embed cast f32 -> bf16 (whole [V,H] matrix) ----------------
__global__ __launch_bounds__(256) void cast_embed_kernel(const float* __restrict__ src,
                                                         unsigned short* __restrict__ dst) {
    size_t g = (size_t)blockIdx.x * 256 + threadIdx.x;   // one float4 per thread
    const float4 v = *(const float4*)(src + g * 4);
    ushort4 u;
    u.x = f2bf(v.x); u.y = f2bf(v.y); u.z = f2bf(v.z); u.w = f2bf(v.w);
    *(ushort4*)(dst + g * 4) = u;
}

// ---------------- embedding gather ----------------
__global__ __launch_bounds__(192) void gather_kernel(const int* __restrict__ tokens,
                                                     const float* __restrict__ embed,
                                                     float* __restrict__ h) {
    int row = blockIdx.x;                       // 0..4095
    int tok = tokens[row];
    const float4 v = *(const float4*)(embed + (size_t)tok * HDIM + threadIdx.x * 4);
    *(float4*)(h + (size_t)row * HDIM + threadIdx.x * 4) = v;
}

// ---------------- layernorm over H=768 ----------------
__global__ __launch_bounds__(256) void ln_kernel(const float* __restrict__ in,
                                                 float* __restrict__ out,
                                                 const float* __restrict__ w,
                                                 const float* __restrict__ b) {
    int row = blockIdx.x, tid = threadIdx.x;
    const float* x = in + (size_t)row * HDIM;
    float x0 = x[tid], x1 = x[tid + 256], x2 = x[tid + 512];
    float s = x0 + x1 + x2;
    float s2 = x0 * x0 + x1 * x1 + x2 * x2;
    for (int o = 32; o; o >>= 1) { s += __shfl_down(s, o); s2 += __shfl_down(s2, o); }
    __shared__ float red[8];
    int lane = tid & 63, wv = tid >> 6;
    if (lane == 0) { red[wv] = s; red[4 + wv] = s2; }
    __syncthreads();
    s  = red[0] + red[1] + red[2] + red[3];
    s2 = red[4] + red[5] + red[6] + red[7];
    float m   = s * (1.0f / HDIM);
    float var = s2 * (1.0f / HDIM) - m * m;
    float inv = 1.0f / sqrtf(var + 1e-5f);
    float* o_ = out + (size_t)row * HDIM;
    o_[tid]       = (x0 - m) * inv * w[tid]       + b[tid];
    o_[tid + 256] = (x1 - m) * inv * w[tid + 256] + b[tid + 256];
    o_[tid + 512] = (x2 - m) * inv * w[tid + 512] + b[tid + 512];
}

// ---------------- S4D conv-kernel generation: Kk[d][h] = dt_h * sum_n C*B*exp(-dt_h*A_n*d) ----
__global__ __launch_bounds__(128) void s4d_gen_kernel(const float* __restrict__ A_log,  // [N]
                                                      const float* __restrict__ Bm,     // [H,N]
                                                      const float* __restrict__ Cm,     // [H,N]
                                                      const float* __restrict__ log_dt, // [H]
                                                      float* __restrict__ Kk) {         // [KTAPS,H]
    int hh = blockIdx.x;          // 0..767
    int d  = threadIdx.x;         // 0..127
    __shared__ float cb[NDIM], ae[NDIM];
    if (threadIdx.x < NDIM) {
        cb[threadIdx.x] = Bm[(size_t)hh * NDIM + threadIdx.x] * Cm[(size_t)hh * NDIM + threadIdx.x];
        ae[threadIdx.x] = expf(A_log[threadIdx.x]);
    }
    __syncthreads();
    float dt = expf(log_dt[hh]);
    float fd = (float)d;
    float s = 0.f;
    #pragma unroll 8
    for (int n = 0; n < NDIM; ++n) s += cb[n] * expf(-dt * ae[n] * fd);
    Kk[(size_t)d * HDIM + hh] = dt * s;
}

// ---------------- causal depthwise conv + residual: h += conv(x) ----------------
__global__ __launch_bounds__(256) void conv_resid_kernel(const float* __restrict__ x,
                                                         const float* __restrict__ Kk,
                                                         float* __restrict__ h) {
    size_t g = (size_t)blockIdx.x * 256 + threadIdx.x;   // over B*S*H
    int bs = (int)(g / HDIM);
    int hh = (int)(g - (size_t)bs * HDIM);
    int t  = bs & (SEQ - 1);
    int dmax = t + 1 < KTAPS ? t + 1 : KTAPS;
    const float* xp = x + (size_t)bs * HDIM + hh;
    float acc = 0.f;
    for (int d = 0; d < dmax; ++d)
        acc += Kk[(size_t)d * HDIM + hh] * xp[-(ptrdiff_t)d * HDIM];
    h[g] = h[g] + acc;
}

// ---------------- transpose + cast: src f32 [R][C] -> dst bf16 [C][R] ----------------
__global__ __launch_bounds__(256) void transpose_cast_kernel(const float* __restrict__ src,
                                                             unsigned short* __restrict__ dst,
                                                             int R, int C) {
    __shared__ float tile[32][33];
    int tx = threadIdx.x, ty = threadIdx.y;     // (32, 8)
    int gx = blockIdx.x * 32, gy = blockIdx.y * 32;
    #pragma unroll
    for (int i = 0; i < 4; ++i) {
        int ry = ty + i * 8;
        tile[ry][tx] = src[(size_t)(gy + ry) * C + gx + tx];
    }
    __syncthreads();
    #pragma unroll
    for (int i = 0; i < 4; ++i) {
        int ry = ty + i * 8;
        dst[(size_t)(gx + ry) * R + gy + tx] = f2bf(tile[tx][ry]);
    }
}

// ---------------- bf16 MFMA GEMM: C[M,N] = A[M,K](f32) @ Bt[N,K](bf16)^T, epilogue ----
// epi: 0 = plain store, 1 = gelu(x + bias), 2 = x + bias + resid
#define TS 40   // LDS k-stride in shorts (80B rows -> conflict-benign)
__global__ __launch_bounds__(256) void gemm_bt_kernel(const float* __restrict__ A,
                                                      const unsigned short* __restrict__ Bt,
                                                      float* __restrict__ C,
                                                      const float* __restrict__ bias,
                                                      const float* __restrict__ resid,
                                                      int N, int K, int epi) {
    __shared__ unsigned short As[64 * TS];
    __shared__ unsigned short Bs[64 * TS];
    int tid = threadIdx.x;
    int lane = tid & 63, wave = tid >> 6;
    int wm = (wave >> 1) * 32, wn = (wave & 1) * 32;
    size_t bm = blockIdx.y, bn = blockIdx.x;
    const float* Ab = A + bm * 64 * (size_t)K;
    const unsigned short* Bb = Bt + bn * 64 * (size_t)K;

    f32x4 acc[2][2] = {};

    for (int k0 = 0; k0 < K; k0 += 32) {
        __syncthreads();
        #pragma unroll
        for (int i = 0; i < 2; ++i) {
            int q = tid + i * 256;
            int row = q >> 3, kq = (q & 7) * 4;
            const float4 v = *(const float4*)(Ab + (size_t)row * K + k0 + kq);
            ushort4 u;
            u.x = f2bf(v.x); u.y = f2bf(v.y); u.z = f2bf(v.z); u.w = f2bf(v.w);
            *(ushort4*)(&As[row * TS + kq]) = u;
        }
        {
            int row = tid >> 2, kq = (tid & 3) * 8;
            const uint4 v = *(const uint4*)(Bb + (size_t)row * K + k0 + kq);
            *(uint4*)(&Bs[row * TS + kq]) = v;
        }
        __syncthreads();
        int mr = lane & 15, kf = (lane >> 4) * 8;
        bf16x8 a0 = *(const bf16x8*)(&As[(wm + mr) * TS + kf]);
        bf16x8 a1 = *(const bf16x8*)(&As[(wm + 16 + mr) * TS + kf]);
        bf16x8 b0 = *(const bf16x8*)(&Bs[(wn + mr) * TS + kf]);
        bf16x8 b1 = *(const bf16x8*)(&Bs[(wn + 16 + mr) * TS + kf]);
        acc[0][0] = __builtin_amdgcn_mfma_f32_16x16x32_bf16(a0, b0, acc[0][0], 0, 0, 0);
        acc[0][1] = __builtin_amdgcn_mfma_f32_16x16x32_bf16(a0, b1, acc[0][1], 0, 0, 0);
        acc[1][0] = __builtin_amdgcn_mfma_f32_16x16x32_bf16(a1, b0, acc[1][0], 0, 0, 0);
        acc[1][1] = __builtin_amdgcn_mfma_f32_16x16x32_bf16(a1, b1, acc[1][1], 0, 0, 0);
    }

    int mr = lane & 15, rq = (lane >> 4) * 4;
    #pragma unroll
    for (int i = 0; i < 2; ++i) {
        #pragma unroll
        for (int j = 0; j < 2; ++j) {
            int col = (int)bn * 64 + wn + j * 16 + mr;
            #pragma unroll
            for (int r = 0; r < 4; ++r) {
                int row = (int)bm * 64 + wm + i * 16 + rq + r;
                float v = acc[i][j][r];
                if (epi == 1) {
                    v += bias[col];
                    v = 0.5f * v * (1.0f + erff(v * 0.70710678118654752f));
                } else if (epi == 2) {
                    v += bias[col] + resid[(size_t)row * N + col];
                }
                C[(size_t)row * N + col] = v;
            }
        }
    }
}

extern "C" void kernel_launch(void* const* d_in, const int* in_sizes, int n_in,
                              void* d_out, int out_size, void* d_ws, size_t ws_size,
                              hipStream_t stream) {
    const int*   tokens = (const int*)  d_in[0];
    const float* embed  = (const float*)d_in[1];
    const float* ln1_w  = (const float*)d_in[2];
    const float* ln1_b  = (const float*)d_in[3];
    const float* A_log  = (const float*)d_in[4];
    const float* Bm     = (const float*)d_in[5];
    const float* Cm     = (const float*)d_in[6];
    const float* log_dt = (const float*)d_in[7];
    const float* ln2_w  = (const float*)d_in[8];
    const float* ln2_b  = (const float*)d_in[9];
    const float* W1     = (const float*)d_in[10];
    const float* b1     = (const float*)d_in[11];
    const float* W2     = (const float*)d_in[12];
    const float* b2     = (const float*)d_in[13];
    const float* lnf_w  = (const float*)d_in[14];
    const float* lnf_b  = (const float*)d_in[15];
    float* out = (float*)d_out;

    // workspace layout
    float* h   = (float*)d_ws;                       // 4096*768
    float* xb  = h  + (size_t)MROWS * HDIM;          // 4096*768
    float* G   = xb + (size_t)MROWS * HDIM;          // 4096*3072
    float* Kk  = G  + (size_t)MROWS * H4DIM;         // 128*768
    unsigned short* w1t = (unsigned short*)(Kk + (size_t)KTAPS * HDIM);  // 3072*768
    unsigned short* w2t = w1t + (size_t)H4DIM * HDIM;                     // 768*3072
    unsigned short* ebf = w2t + (size_t)H4DIM * HDIM;                     // 32000*768

    // embed -> bf16 [V][H]  (B^T layout for the head GEMM)
    cast_embed_kernel<<<(VOCAB * HDIM) / 1024, 256, 0, stream>>>(embed, ebf);
    // h = embed[tokens]
    gather_kernel<<<MROWS, 192, 0, stream>>>(tokens, embed, h);

    for (int l = 0; l < 6; ++l) {
        // S4D conv taps for this layer
        s4d_gen_kernel<<<HDIM, 128, 0, stream>>>(A_log + l * NDIM,
                                                 Bm + (size_t)l * HDIM * NDIM,
                                                 Cm + (size_t)l * HDIM * NDIM,
                                                 log_dt + l * HDIM, Kk);
        // x = LN1(h)
        ln_kernel<<<MROWS, 256, 0, stream>>>(h, xb, ln1_w + l * HDIM, ln1_b + l * HDIM);
        // h += conv(x)
        conv_resid_kernel<<<(MROWS * HDIM) / 256, 256, 0, stream>>>(xb, Kk, h);
        // z = LN2(h)
        ln_kernel<<<MROWS, 256, 0, stream>>>(h, xb, ln2_w + l * HDIM, ln2_b + l * HDIM);
        // weight transposes+casts: W1[H,4H] -> [4H][H] bf16 ; W2[4H,H] -> [H][4H] bf16
        transpose_cast_kernel<<<dim3(H4DIM / 32, HDIM / 32), dim3(32, 8), 0, stream>>>(
            W1 + (size_t)l * HDIM * H4DIM, w1t, HDIM, H4DIM);
        transpose_cast_kernel<<<dim3(HDIM / 32, H4DIM / 32), dim3(32, 8), 0, stream>>>(
            W2 + (size_t)l * HDIM * H4DIM, w2t, H4DIM, HDIM);
        // G = gelu(z @ W1 + b1)
        gemm_bt_kernel<<<dim3(H4DIM / 64, MROWS / 64), 256, 0, stream>>>(
            xb, w1t, G, b1 + l * H4DIM, nullptr, H4DIM, HDIM, 1);
        // h = h + (G @ W2 + b2)
        gemm_bt_kernel<<<dim3(HDIM / 64, MROWS / 64), 256, 0, stream>>>(
            G, w2t, h, b2 + l * HDIM, h, HDIM, H4DIM, 2);
    }

    // hf = LNF(h)
    ln_kernel<<<MROWS, 256, 0, stream>>>(h, xb, lnf_w, lnf_b);
    // logits = hf @ embed^T
    gemm_bt_kernel<<<dim3(VOCAB / 64, MROWS / 64), 256, 0, stream>>>(
        xb, ebf, out, nullptr, nullptr, VOCAB, HDIM, 0);
}